// Round 6
// baseline (375.345 us; speedup 1.0000x reference)
//
#include <hip/hip_runtime.h>
#include <math.h>

#define SEQ    2048
#define EMBED  1024
#define HEADS  16
#define HDIM   64
#define BATCH  4
#define ROWS   (BATCH * SEQ)    // 8192
#define BH     (BATCH * HEADS)  // 64

typedef _Float16 f16;
typedef __attribute__((ext_vector_type(2))) _Float16 f16x2;
typedef __attribute__((ext_vector_type(4))) _Float16 f16x4;
typedef __attribute__((ext_vector_type(8))) _Float16 f16x8;
typedef __attribute__((ext_vector_type(4)))  float   f32x4;
typedef __attribute__((ext_vector_type(16))) float   f32x16;

#define EXP2C 0.14426950408889634f   // 0.1 * log2(e)

__device__ __forceinline__ void async16(void* l, const void* g) {
    __builtin_amdgcn_global_load_lds(
        (__attribute__((address_space(1))) void*)(uintptr_t)g,
        (__attribute__((address_space(3))) void*)(uint32_t)(uintptr_t)l,
        16, 0, 0);
}
__device__ __forceinline__ f32x4 mfma16(f16x8 a, f16x8 b, f32x4 c) {
    return __builtin_amdgcn_mfma_f32_16x16x32_f16(a, b, c, 0, 0, 0);
}
__device__ __forceinline__ f32x16 mfma32(f16x8 a, f16x8 b, f32x16 c) {
    return __builtin_amdgcn_mfma_f32_32x32x16_f16(a, b, c, 0, 0, 0);
}
__device__ __forceinline__ f32x16 zero16() {
    f32x16 z;
#pragma unroll
    for (int i = 0; i < 16; ++i) z[i] = 0.f;
    return z;
}
// pack two floats to f16x2 (RTZ)
__device__ __forceinline__ f16x2 pk2(float a, float b) {
    union {
        __fp16 __attribute__((ext_vector_type(2))) h;
        f16x2 f;
    } u;
    u.h = __builtin_amdgcn_cvt_pkrtz(a, b);
    return u.f;
}
// f16 offset of swizzled 16B granule `gran` in a 64-f16 (128B, 8-granule) row
__device__ __forceinline__ int swz64(int row, int gran) {
    return row * 64 + ((gran ^ (row & 7)) << 3);
}

// ---------------------------------------------------------------------------
// Kernel 0: fp32 -> fp16 convert. x -> xh; Wq/Wk/Wv -> Wh concat [3072][1024].
// ---------------------------------------------------------------------------
#define NX4 (ROWS * EMBED / 4)
#define NW4 (EMBED * EMBED / 4)
__global__ __launch_bounds__(256) void cvt_kernel(
    const float* __restrict__ x,
    const float* __restrict__ Wq, const float* __restrict__ Wk,
    const float* __restrict__ Wv,
    f16* __restrict__ xh, f16* __restrict__ Wh)
{
    int i = blockIdx.x * 256 + threadIdx.x;
    const float4* src; f16* dst; int j;
    if (i < NX4)              { src = (const float4*)x;  dst = xh;                j = i; }
    else if (i < NX4 + NW4)   { src = (const float4*)Wq; dst = Wh;                j = i - NX4; }
    else if (i < NX4 + 2*NW4) { src = (const float4*)Wk; dst = Wh + EMBED*EMBED;  j = i - NX4 - NW4; }
    else                      { src = (const float4*)Wv; dst = Wh + 2*EMBED*EMBED;j = i - NX4 - 2*NW4; }
    float4 v = src[j];
    f16x4 h;
    h[0] = (f16)v.x; h[1] = (f16)v.y; h[2] = (f16)v.z; h[3] = (f16)v.w;
    *(f16x4*)(dst + (size_t)j * 4) = h;
}

// ---------------------------------------------------------------------------
// Kernel 1: fused QKV projection (f16 MFMA 16x16x32, swizzled LDS,
// double-buffered: prefetch k-tile it+1 while computing it, ONE barrier/iter).
// Plain 2-D shared arrays; separate Ts (no aliasing).
// Q,K -> [bh][s][d]; V -> LDS-transposed into Vt [bh][d][s].
// ---------------------------------------------------------------------------
__global__ __launch_bounds__(256) void proj_kernel(
    const f16* __restrict__ A,   // [8192][1024]
    const f16* __restrict__ W,   // [3072][1024]
    const float* __restrict__ bq, const float* __restrict__ bk,
    const float* __restrict__ bv,
    f16* __restrict__ Qh, f16* __restrict__ Kh, f16* __restrict__ Vt)
{
    __shared__ f16 Asb[2][4096];   // [buf][128 rows x 32 f16], swizzled
    __shared__ f16 Bsb[2][4096];
    __shared__ f16 Ts[64 * 132];   // V transpose staging (epilogue only)

    const int t = threadIdx.x, wv = t >> 6, lane = t & 63;
    const int lm = lane & 15, quad = lane >> 4;
    const int r0 = blockIdx.x * 128, c0 = blockIdx.y * 128;
    const int wm = wv & 1, wn = wv >> 1;

    const int srow = lane >> 2;
    const int sgr  = (lane & 3) ^ (srow & 3);
    const f16* gA = A + (size_t)(r0 + wv * 32 + srow) * EMBED + sgr * 8;
    const f16* gB = W + (size_t)(c0 + wv * 32 + srow) * EMBED + sgr * 8;

    f32x4 acc[4][4];
#pragma unroll
    for (int i = 0; i < 4; ++i)
#pragma unroll
        for (int j = 0; j < 4; ++j) acc[i][j] = (f32x4){0.f, 0.f, 0.f, 0.f};

    // prologue: tile 0 into buf 0
    async16(&Asb[0][wv * 1024],       gA);
    async16(&Asb[0][wv * 1024 + 512], gA + (size_t)16 * EMBED);
    async16(&Bsb[0][wv * 1024],       gB);
    async16(&Bsb[0][wv * 1024 + 512], gB + (size_t)16 * EMBED);
    __syncthreads();

    for (int it = 0; it < 32; ++it) {
        const int cur = it & 1;
        if (it + 1 < 32) {
            const int kk = (it + 1) * 32;
            async16(&Asb[cur ^ 1][wv * 1024],       gA + kk);
            async16(&Asb[cur ^ 1][wv * 1024 + 512], gA + (size_t)16 * EMBED + kk);
            async16(&Bsb[cur ^ 1][wv * 1024],       gB + kk);
            async16(&Bsb[cur ^ 1][wv * 1024 + 512], gB + (size_t)16 * EMBED + kk);
        }
        f16x8 af[4], bf[4];
#pragma unroll
        for (int i = 0; i < 4; ++i) {
            int row = wm * 64 + i * 16 + lm;
            af[i] = *(const f16x8*)&Asb[cur][row * 32 + ((quad ^ (row & 3)) << 3)];
        }
#pragma unroll
        for (int i = 0; i < 4; ++i) {
            int row = wn * 64 + i * 16 + lm;
            bf[i] = *(const f16x8*)&Bsb[cur][row * 32 + ((quad ^ (row & 3)) << 3)];
        }
#pragma unroll
        for (int mi = 0; mi < 4; ++mi)
#pragma unroll
            for (int ni = 0; ni < 4; ++ni)
                acc[mi][ni] = mfma16(af[mi], bf[ni], acc[mi][ni]);
        __syncthreads();
    }

    const int z = c0 >> 10;              // 0=Q 1=K 2=V
    const float* bias = (z == 0) ? bq : (z == 1) ? bk : bv;
    const int b  = r0 >> 11;
    const int s0 = r0 & 2047;

    if (z < 2) {
        f16* O = (z == 0) ? Qh : Kh;
#pragma unroll
        for (int ni = 0; ni < 4; ++ni) {
            int cz = (c0 & 1023) + wn * 64 + ni * 16 + lm;
            float bb = bias[cz];
            int h = cz >> 6, d = cz & 63;
#pragma unroll
            for (int mi = 0; mi < 4; ++mi) {
                int s = s0 + wm * 64 + mi * 16 + quad * 4;
                size_t base = ((size_t)(b * HEADS + h) * SEQ + s) * HDIM + d;
#pragma unroll
                for (int r = 0; r < 4; ++r)
                    O[base + (size_t)r * HDIM] = (f16)(acc[mi][ni][r] + bb);
            }
        }
    } else {
        // V: transpose through LDS, store Vt[bh][d][s] coalesced
#pragma unroll 1
        for (int hd = 0; hd < 2; ++hd) {
            __syncthreads();
            if (wn == hd) {
#pragma unroll
                for (int ni = 0; ni < 4; ++ni) {
                    int cz = (c0 & 1023) + wn * 64 + ni * 16 + lm;
                    float bb = bias[cz];
                    int dloc = ni * 16 + lm;       // 0..63 within this head
#pragma unroll
                    for (int mi = 0; mi < 4; ++mi) {
                        int sloc = wm * 64 + mi * 16 + quad * 4;
                        f16x4 pk;
#pragma unroll
                        for (int r = 0; r < 4; ++r) pk[r] = (f16)(acc[mi][ni][r] + bb);
                        *(f16x4*)&Ts[dloc * 132 + sloc] = pk;
                    }
                }
            }
            __syncthreads();
            int hout = ((c0 & 1023) >> 6) + hd;
            int dl = t >> 2, soff = (t & 3) * 32;
            size_t gbase = ((size_t)(b * HEADS + hout) * HDIM + dl) * SEQ + s0 + soff;
#pragma unroll
            for (int c = 0; c < 8; ++c) {
                f16x4 v = *(const f16x4*)&Ts[dl * 132 + soff + 4 * c];
                *(f16x4*)&Vt[gbase + 4 * c] = v;
            }
        }
    }
}

// ---------------------------------------------------------------------------
// Kernel 2: column stats + V fold.  cs[k] = sum_q exp(S[q,k]/10); then
// Vt[bh][d][k] *= 64/cs[k] in place.  K pinned in regs; Q double-buffered.
// ---------------------------------------------------------------------------
__global__ __launch_bounds__(256) void stats_kernel(
    const f16* __restrict__ Qh, const f16* __restrict__ Kh,
    f16* __restrict__ Vt)
{
    __shared__ f16 Kst[256 * 64];      // 32KB
    __shared__ f16 Qsb2[2][64 * 64];   // 16KB
    __shared__ f16 Ls[256];

    const int t = threadIdx.x, wv = t >> 6, lane = t & 63;
    const int lm = lane & 31, half = lane >> 5;
    const int bh = blockIdx.y, k0 = blockIdx.x * 256;
    const size_t base  = (size_t)bh * SEQ * HDIM;
    const size_t vbase = (size_t)bh * HDIM * SEQ;

    const int srow = lane >> 3;                 // 0..7 (8 rows / glds instr)
    const int sgr  = (lane & 7) ^ (srow & 7);   // swizzled granule

    // stage all 256 K rows + Q tile 0
#pragma unroll
    for (int i = 0; i < 8; ++i) {
        int rr = wv * 64 + 8 * i;
        async16(Kst + rr * 64,
                Kh + base + (size_t)(k0 + rr + srow) * 64 + sgr * 8);
    }
#pragma unroll
    for (int i = 0; i < 2; ++i) {
        int rr = wv * 16 + 8 * i;
        async16(&Qsb2[0][rr * 64],
                Qh + base + (size_t)(rr + srow) * 64 + sgr * 8);
    }
    __syncthreads();

    f16x8 Kf[2][4];
#pragma unroll
    for (int kt = 0; kt < 2; ++kt)
#pragma unroll
        for (int kg = 0; kg < 4; ++kg)
            Kf[kt][kg] = *(const f16x8*)&Kst[swz64(wv * 64 + kt * 32 + lm, 2 * kg + half)];

    float cs0 = 0.f, cs1 = 0.f;
    for (int it = 0; it < 32; ++it) {
        const int cur = it & 1;
        if (it + 1 < 32) {
            const int q0 = (it + 1) * 64;
#pragma unroll
            for (int i = 0; i < 2; ++i) {
                int rr = wv * 16 + 8 * i;
                async16(&Qsb2[cur ^ 1][rr * 64],
                        Qh + base + (size_t)(q0 + rr + srow) * 64 + sgr * 8);
            }
        }
#pragma unroll
        for (int qt = 0; qt < 2; ++qt) {
            f16x8 Qf[4];
#pragma unroll
            for (int kg = 0; kg < 4; ++kg)
                Qf[kg] = *(const f16x8*)&Qsb2[cur][swz64(qt * 32 + lm, 2 * kg + half)];
            f32x16 s0v = zero16(), s1v = zero16();
#pragma unroll
            for (int kg = 0; kg < 4; ++kg) {
                s0v = mfma32(Qf[kg], Kf[0][kg], s0v);
                s1v = mfma32(Qf[kg], Kf[1][kg], s1v);
            }
#pragma unroll
            for (int e = 0; e < 16; ++e) {
                cs0 += exp2f(s0v[e] * EXP2C);
                cs1 += exp2f(s1v[e] * EXP2C);
            }
        }
        __syncthreads();
    }
    cs0 += __shfl_xor(cs0, 32, 64);
    cs1 += __shfl_xor(cs1, 32, 64);
    if (half == 0) {
        Ls[wv * 64 + lm]      = (f16)(64.0f / cs0);
        Ls[wv * 64 + 32 + lm] = (f16)(64.0f / cs1);
    }
    __syncthreads();

    // V fold: Vt[bh][d][k0..k0+255] *= Ls (in place)
    {
        int dl = t >> 2, koff = (t & 3) * 64;
        size_t g = vbase + (size_t)dl * SEQ + k0 + koff;
#pragma unroll
        for (int c = 0; c < 8; ++c) {
            f16x8 v  = *(const f16x8*)&Vt[g + 8 * c];
            f16x8 lv = *(const f16x8*)&Ls[koff + 8 * c];
            v = v * lv;
            *(f16x8*)&Vt[g + 8 * c] = v;
        }
    }
}

// ---------------------------------------------------------------------------
// Kernel 3: out[q,d] = (1/64) * sum_k exp(S[q,k]/10) * V''[k,d].
// 32x32x16 MFMA; wave = 64 q rows; K/V double-buffered (prefetch tile it+1
// during compute of it, one barrier/iter). S^T = K.Q^T -> P packed into
// per-wave swizzled LDS (overlays Q staging); PV = P @ V''.
// ---------------------------------------------------------------------------
__global__ __launch_bounds__(256) void out_kernel(
    const f16* __restrict__ Qh, const f16* __restrict__ Kh,
    const f16* __restrict__ Vt, float* __restrict__ out)
{
    __shared__ f16 Qs[256 * 64];       // 32KB; per-wave 8KB regions become P
    __shared__ f16 Ksb[2][64 * 64];    // 16KB
    __shared__ f16 Vsb[2][64 * 64];    // 16KB

    const int t = threadIdx.x, wv = t >> 6, lane = t & 63;
    const int lm = lane & 31, half = lane >> 5;
    const int bh = blockIdx.y, q0 = blockIdx.x * 256;
    const int b = bh >> 4, h = bh & 15;
    const size_t base  = (size_t)bh * SEQ * HDIM;
    const size_t vbase = (size_t)bh * HDIM * SEQ;

    const int srow = lane >> 3;
    const int sgr  = (lane & 7) ^ (srow & 7);

    // stage this wave's 64 Q rows + K/V tile 0
#pragma unroll
    for (int i = 0; i < 8; ++i) {
        int rr = wv * 64 + 8 * i;
        async16(Qs + rr * 64,
                Qh + base + (size_t)(q0 + rr + srow) * 64 + sgr * 8);
    }
#pragma unroll
    for (int i = 0; i < 2; ++i) {
        int rr = wv * 16 + 8 * i;
        async16(&Ksb[0][rr * 64],
                Kh + base + (size_t)(rr + srow) * 64 + sgr * 8);
        async16(&Vsb[0][rr * 64],
                Vt + vbase + (size_t)(rr + srow) * SEQ + sgr * 8);
    }
    __syncthreads();

    f16x8 Qf[2][4];   // B-operand for S^T: B[d][q], pinned
#pragma unroll
    for (int qt = 0; qt < 2; ++qt)
#pragma unroll
        for (int kg = 0; kg < 4; ++kg)
            Qf[qt][kg] = *(const f16x8*)&Qs[swz64(wv * 64 + qt * 32 + lm, 2 * kg + half)];

    f32x16 oacc[2][2];
#pragma unroll
    for (int i = 0; i < 2; ++i)
#pragma unroll
        for (int j = 0; j < 2; ++j) oacc[i][j] = zero16();

    f16* Pw = Qs + wv * 64 * 64;   // per-wave P region [64 q][64 k], swizzled

    for (int it = 0; it < 32; ++it) {
        const int cur = it & 1;
        if (it + 1 < 32) {
            const int k0 = (it + 1) * 64;
#pragma unroll
            for (int i = 0; i < 2; ++i) {
                int rr = wv * 16 + 8 * i;
                async16(&Ksb[cur ^ 1][rr * 64],
                        Kh + base + (size_t)(k0 + rr + srow) * 64 + sgr * 8);
                async16(&Vsb[cur ^ 1][rr * 64],
                        Vt + vbase + (size_t)(rr + srow) * SEQ + k0 + sgr * 8);
            }
        }

        // S^T tiles: D[m=k][n=q] = K . Q^T ; exp ; pack k-contiguous into Pw
#pragma unroll
        for (int kt = 0; kt < 2; ++kt) {
            f16x8 Kfr[4];
#pragma unroll
            for (int kg = 0; kg < 4; ++kg)
                Kfr[kg] = *(const f16x8*)&Ksb[cur][swz64(kt * 32 + lm, 2 * kg + half)];
#pragma unroll
            for (int qt = 0; qt < 2; ++qt) {
                f32x16 st = zero16();
#pragma unroll
                for (int kg = 0; kg < 4; ++kg)
                    st = mfma32(Kfr[kg], Qf[qt][kg], st);
                int row = qt * 32 + lm;   // P row (q-local)
#pragma unroll
                for (int g = 0; g < 4; ++g) {
                    union { f16x2 h2[2]; f16x4 h4; } u;
                    u.h2[0] = pk2(exp2f(st[4*g+0] * EXP2C), exp2f(st[4*g+1] * EXP2C));
                    u.h2[1] = pk2(exp2f(st[4*g+2] * EXP2C), exp2f(st[4*g+3] * EXP2C));
                    *(f16x4*)&Pw[row * 64 + (((4*kt+g) ^ (row & 7)) << 3) + half * 4] = u.h4;
                }
            }
        }

        // PV: D[m=q][n=d] = P @ V''  (same-wave DS ordering, no barrier)
        f16x8 Vf[2][4];
#pragma unroll
        for (int dt = 0; dt < 2; ++dt)
#pragma unroll
            for (int kc = 0; kc < 4; ++kc)
                Vf[dt][kc] = *(const f16x8*)&Vsb[cur][swz64(dt * 32 + lm, 2 * kc + half)];
#pragma unroll
        for (int qt = 0; qt < 2; ++qt) {
            int row = qt * 32 + lm;
#pragma unroll
            for (int kc = 0; kc < 4; ++kc) {
                f16x8 Pf = *(const f16x8*)&Pw[row * 64 + (((2*kc+half) ^ (row & 7)) << 3)];
                oacc[qt][0] = mfma32(Pf, Vf[0][kc], oacc[qt][0]);
                oacc[qt][1] = mfma32(Pf, Vf[1][kc], oacc[qt][1]);
            }
        }
        __syncthreads();
    }

    // store: C col = d (lane&31), rows = q pattern
#pragma unroll
    for (int qt = 0; qt < 2; ++qt)
#pragma unroll
        for (int dt = 0; dt < 2; ++dt) {
            int col = h * HDIM + dt * 32 + lm;
#pragma unroll
            for (int e = 0; e < 16; ++e) {
                int s = q0 + wv * 64 + qt * 32 + (e & 3) + 8 * (e >> 2) + 4 * half;
                out[((size_t)b * SEQ + s) * EMBED + col] = oacc[qt][dt][e] * 0.015625f;
            }
        }
}

extern "C" void kernel_launch(void* const* d_in, const int* in_sizes, int n_in,
                              void* d_out, int out_size, void* d_ws, size_t ws_size,
                              hipStream_t stream) {
    const float* x  = (const float*)d_in[0];
    const float* Wq = (const float*)d_in[1];
    const float* bq = (const float*)d_in[2];
    const float* Wk = (const float*)d_in[3];
    const float* bk = (const float*)d_in[4];
    const float* Wv = (const float*)d_in[5];
    const float* bv = (const float*)d_in[6];
    float* out = (float*)d_out;

    f16* xh = (f16*)d_ws;                          // 8.4M f16
    f16* Wh = xh + (size_t)ROWS * EMBED;           // 3.1M
    f16* Qh = Wh + (size_t)3 * EMBED * EMBED;      // 8.4M
    f16* Kh = Qh + (size_t)BH * SEQ * HDIM;        // 8.4M
    f16* Vt = Kh + (size_t)BH * SEQ * HDIM;        // 8.4M  [bh][d][s]

    cvt_kernel<<<(NX4 + 3 * NW4) / 256, 256, 0, stream>>>(x, Wq, Wk, Wv, xh, Wh);
    proj_kernel<<<dim3(ROWS / 128, 3 * EMBED / 128), 256, 0, stream>>>(
        xh, Wh, bq, bk, bv, Qh, Kh, Vt);
    stats_kernel<<<dim3(SEQ / 256, BH), 256, 0, stream>>>(Qh, Kh, Vt);
    out_kernel<<<dim3(SEQ / 256, BH), 256, 0, stream>>>(Qh, Kh, Vt, out);
}

// Round 7
// 358.078 us; speedup vs baseline: 1.0482x; 1.0482x over previous
//
#include <hip/hip_runtime.h>
#include <math.h>

#define SEQ    2048
#define EMBED  1024
#define HEADS  16
#define HDIM   64
#define BATCH  4
#define ROWS   (BATCH * SEQ)    // 8192
#define BH     (BATCH * HEADS)  // 64

typedef _Float16 f16;
typedef __attribute__((ext_vector_type(2))) _Float16 f16x2;
typedef __attribute__((ext_vector_type(4))) _Float16 f16x4;
typedef __attribute__((ext_vector_type(8))) _Float16 f16x8;
typedef __attribute__((ext_vector_type(4)))  float   f32x4;
typedef __attribute__((ext_vector_type(16))) float   f32x16;

#define EXP2C 0.14426950408889634f   // 0.1 * log2(e), folded into Q at proj

__device__ __forceinline__ void async16(void* l, const void* g) {
    __builtin_amdgcn_global_load_lds(
        (__attribute__((address_space(1))) void*)(uintptr_t)g,
        (__attribute__((address_space(3))) void*)(uint32_t)(uintptr_t)l,
        16, 0, 0);
}
__device__ __forceinline__ f32x4 mfma16(f16x8 a, f16x8 b, f32x4 c) {
    return __builtin_amdgcn_mfma_f32_16x16x32_f16(a, b, c, 0, 0, 0);
}
__device__ __forceinline__ f32x16 mfma32(f16x8 a, f16x8 b, f32x16 c) {
    return __builtin_amdgcn_mfma_f32_32x32x16_f16(a, b, c, 0, 0, 0);
}
__device__ __forceinline__ f32x16 zero16() {
    f32x16 z;
#pragma unroll
    for (int i = 0; i < 16; ++i) z[i] = 0.f;
    return z;
}
// pack two floats to f16x2 (RTZ)
__device__ __forceinline__ f16x2 pk2(float a, float b) {
    union {
        __fp16 __attribute__((ext_vector_type(2))) h;
        f16x2 f;
    } u;
    u.h = __builtin_amdgcn_cvt_pkrtz(a, b);
    return u.f;
}
// f16 offset of swizzled 16B granule `gran` in a 64-f16 (128B, 8-granule) row
__device__ __forceinline__ int swz64(int row, int gran) {
    return row * 64 + ((gran ^ (row & 7)) << 3);
}

// ---------------------------------------------------------------------------
// Kernel 0: fp32 -> fp16 convert. x -> xh; Wq/Wk/Wv -> Wh concat [3072][1024].
// ---------------------------------------------------------------------------
#define NX4 (ROWS * EMBED / 4)
#define NW4 (EMBED * EMBED / 4)
__global__ __launch_bounds__(256) void cvt_kernel(
    const float* __restrict__ x,
    const float* __restrict__ Wq, const float* __restrict__ Wk,
    const float* __restrict__ Wv,
    f16* __restrict__ xh, f16* __restrict__ Wh)
{
    int i = blockIdx.x * 256 + threadIdx.x;
    const float4* src; f16* dst; int j;
    if (i < NX4)              { src = (const float4*)x;  dst = xh;                j = i; }
    else if (i < NX4 + NW4)   { src = (const float4*)Wq; dst = Wh;                j = i - NX4; }
    else if (i < NX4 + 2*NW4) { src = (const float4*)Wk; dst = Wh + EMBED*EMBED;  j = i - NX4 - NW4; }
    else                      { src = (const float4*)Wv; dst = Wh + 2*EMBED*EMBED;j = i - NX4 - 2*NW4; }
    float4 v = src[j];
    f16x4 h;
    h[0] = (f16)v.x; h[1] = (f16)v.y; h[2] = (f16)v.z; h[3] = (f16)v.w;
    *(f16x4*)(dst + (size_t)j * 4) = h;
}

// ---------------------------------------------------------------------------
// Kernel 1: fused QKV projection (f16 MFMA 16x16x32, swizzled LDS, dbuf).
// Q gets the softmax exp2 scale folded in (Q *= 0.1*log2e).
// Q,K -> [bh][s][d]; V -> LDS-transposed into Vt [bh][d][s].
// ---------------------------------------------------------------------------
__global__ __launch_bounds__(256) void proj_kernel(
    const f16* __restrict__ A,   // [8192][1024]
    const f16* __restrict__ W,   // [3072][1024]
    const float* __restrict__ bq, const float* __restrict__ bk,
    const float* __restrict__ bv,
    f16* __restrict__ Qh, f16* __restrict__ Kh, f16* __restrict__ Vt)
{
    __shared__ f16 Asb[2][4096];   // [buf][128 rows x 32 f16], swizzled
    __shared__ f16 Bsb[2][4096];
    __shared__ f16 Ts[64 * 132];   // V transpose staging (epilogue only)

    const int t = threadIdx.x, wv = t >> 6, lane = t & 63;
    const int lm = lane & 15, quad = lane >> 4;
    const int r0 = blockIdx.x * 128, c0 = blockIdx.y * 128;
    const int wm = wv & 1, wn = wv >> 1;

    const int srow = lane >> 2;
    const int sgr  = (lane & 3) ^ (srow & 3);
    const f16* gA = A + (size_t)(r0 + wv * 32 + srow) * EMBED + sgr * 8;
    const f16* gB = W + (size_t)(c0 + wv * 32 + srow) * EMBED + sgr * 8;

    f32x4 acc[4][4];
#pragma unroll
    for (int i = 0; i < 4; ++i)
#pragma unroll
        for (int j = 0; j < 4; ++j) acc[i][j] = (f32x4){0.f, 0.f, 0.f, 0.f};

    // prologue: tile 0 into buf 0
    async16(&Asb[0][wv * 1024],       gA);
    async16(&Asb[0][wv * 1024 + 512], gA + (size_t)16 * EMBED);
    async16(&Bsb[0][wv * 1024],       gB);
    async16(&Bsb[0][wv * 1024 + 512], gB + (size_t)16 * EMBED);
    __syncthreads();

    for (int it = 0; it < 32; ++it) {
        const int cur = it & 1;
        if (it + 1 < 32) {
            const int kk = (it + 1) * 32;
            async16(&Asb[cur ^ 1][wv * 1024],       gA + kk);
            async16(&Asb[cur ^ 1][wv * 1024 + 512], gA + (size_t)16 * EMBED + kk);
            async16(&Bsb[cur ^ 1][wv * 1024],       gB + kk);
            async16(&Bsb[cur ^ 1][wv * 1024 + 512], gB + (size_t)16 * EMBED + kk);
        }
        f16x8 af[4], bf[4];
#pragma unroll
        for (int i = 0; i < 4; ++i) {
            int row = wm * 64 + i * 16 + lm;
            af[i] = *(const f16x8*)&Asb[cur][row * 32 + ((quad ^ (row & 3)) << 3)];
        }
#pragma unroll
        for (int i = 0; i < 4; ++i) {
            int row = wn * 64 + i * 16 + lm;
            bf[i] = *(const f16x8*)&Bsb[cur][row * 32 + ((quad ^ (row & 3)) << 3)];
        }
#pragma unroll
        for (int mi = 0; mi < 4; ++mi)
#pragma unroll
            for (int ni = 0; ni < 4; ++ni)
                acc[mi][ni] = mfma16(af[mi], bf[ni], acc[mi][ni]);
        __syncthreads();
    }

    const int z = c0 >> 10;              // 0=Q 1=K 2=V
    const float* bias = (z == 0) ? bq : (z == 1) ? bk : bv;
    const int b  = r0 >> 11;
    const int s0 = r0 & 2047;

    if (z < 2) {
        f16* O = (z == 0) ? Qh : Kh;
        const float scl = (z == 0) ? EXP2C : 1.0f;   // fold exp2 arg scale into Q
#pragma unroll
        for (int ni = 0; ni < 4; ++ni) {
            int cz = (c0 & 1023) + wn * 64 + ni * 16 + lm;
            float bb = bias[cz];
            int h = cz >> 6, d = cz & 63;
#pragma unroll
            for (int mi = 0; mi < 4; ++mi) {
                int s = s0 + wm * 64 + mi * 16 + quad * 4;
                size_t base = ((size_t)(b * HEADS + h) * SEQ + s) * HDIM + d;
#pragma unroll
                for (int r = 0; r < 4; ++r)
                    O[base + (size_t)r * HDIM] = (f16)((acc[mi][ni][r] + bb) * scl);
            }
        }
    } else {
        // V: transpose through LDS, store Vt[bh][d][s] coalesced
#pragma unroll 1
        for (int hd = 0; hd < 2; ++hd) {
            __syncthreads();
            if (wn == hd) {
#pragma unroll
                for (int ni = 0; ni < 4; ++ni) {
                    int cz = (c0 & 1023) + wn * 64 + ni * 16 + lm;
                    float bb = bias[cz];
                    int dloc = ni * 16 + lm;       // 0..63 within this head
#pragma unroll
                    for (int mi = 0; mi < 4; ++mi) {
                        int sloc = wm * 64 + mi * 16 + quad * 4;
                        f16x4 pk;
#pragma unroll
                        for (int r = 0; r < 4; ++r) pk[r] = (f16)(acc[mi][ni][r] + bb);
                        *(f16x4*)&Ts[dloc * 132 + sloc] = pk;
                    }
                }
            }
            __syncthreads();
            int hout = ((c0 & 1023) >> 6) + hd;
            int dl = t >> 2, soff = (t & 3) * 32;
            size_t gbase = ((size_t)(b * HEADS + hout) * HDIM + dl) * SEQ + s0 + soff;
#pragma unroll
            for (int c = 0; c < 8; ++c) {
                f16x4 v = *(const f16x4*)&Ts[dl * 132 + soff + 4 * c];
                *(f16x4*)&Vt[gbase + 4 * c] = v;
            }
        }
    }
}

// ---------------------------------------------------------------------------
// Kernel 2: column stats + V fold.  cs[k] = sum_q exp2(Qs.K); then
// Vt[bh][d][k] *= 64/cs[k] in place.  Block = 128 k-cols (32/wave, pinned),
// grid (16,64) = 1024 blocks = 4/CU; LDS 24KB.
// ---------------------------------------------------------------------------
__global__ __launch_bounds__(256) void stats_kernel(
    const f16* __restrict__ Qh, const f16* __restrict__ Kh,
    f16* __restrict__ Vt)
{
    __shared__ f16 Kst[128 * 64];   // 16KB
    __shared__ f16 Qs[64 * 64];     // 8KB
    __shared__ f16 Ls[128];

    const int t = threadIdx.x, wv = t >> 6, lane = t & 63;
    const int lm = lane & 31, half = lane >> 5;
    const int bh = blockIdx.y, k0 = blockIdx.x * 128;
    const size_t base  = (size_t)bh * SEQ * HDIM;
    const size_t vbase = (size_t)bh * HDIM * SEQ;

    const int srow = lane >> 3;                 // 0..7 (8 rows / glds instr)
    const int sgr  = (lane & 7) ^ (srow & 7);   // swizzled granule

    // stage 128 K rows (32/wave) + nothing else yet
#pragma unroll
    for (int i = 0; i < 4; ++i) {
        int rr = wv * 32 + 8 * i;
        async16(Kst + rr * 64,
                Kh + base + (size_t)(k0 + rr + srow) * 64 + sgr * 8);
    }
    __syncthreads();

    f16x8 Kf[4];   // this wave's 32 k-cols, pinned for the whole q sweep
#pragma unroll
    for (int kg = 0; kg < 4; ++kg)
        Kf[kg] = *(const f16x8*)&Kst[swz64(wv * 32 + lm, 2 * kg + half)];

    float cs = 0.f;
    for (int q0 = 0; q0 < SEQ; q0 += 64) {
        __syncthreads();
#pragma unroll
        for (int i = 0; i < 2; ++i) {
            int rr = wv * 16 + 8 * i;
            async16(Qs + rr * 64,
                    Qh + base + (size_t)(q0 + rr + srow) * 64 + sgr * 8);
        }
        __syncthreads();
#pragma unroll
        for (int qt = 0; qt < 2; ++qt) {
            f16x8 Qf[4];
#pragma unroll
            for (int kg = 0; kg < 4; ++kg)
                Qf[kg] = *(const f16x8*)&Qs[swz64(qt * 32 + lm, 2 * kg + half)];
            f32x16 sv = zero16();
#pragma unroll
            for (int kg = 0; kg < 4; ++kg)
                sv = mfma32(Qf[kg], Kf[kg], sv);
#pragma unroll
            for (int e = 0; e < 16; ++e)
                cs += exp2f(sv[e]);
        }
    }
    cs += __shfl_xor(cs, 32, 64);
    if (half == 0)
        Ls[wv * 32 + lm] = (f16)(64.0f / cs);
    __syncthreads();

    // V fold: Vt[bh][d][k0..k0+127] *= Ls (in place)
    {
        int dl = t >> 2, koff = (t & 3) * 32;
        size_t g = vbase + (size_t)dl * SEQ + k0 + koff;
#pragma unroll
        for (int c = 0; c < 4; ++c) {
            f16x8 v  = *(const f16x8*)&Vt[g + 8 * c];
            f16x8 lv = *(const f16x8*)&Ls[koff + 8 * c];
            v = v * lv;
            *(f16x8*)&Vt[g + 8 * c] = v;
        }
    }
}

// ---------------------------------------------------------------------------
// Kernel 3: out[q,d] = (1/64) * sum_k exp2(Qs.K) * V''[k,d].
// Block = 128 q rows (32/wave), grid (16,64) = 1024 blocks = 4/CU; LDS 32KB.
// S^T = K.Q^T (C rows = k) -> P packed k-contiguous into per-wave swizzled
// LDS region overlaying the wave's Q staging; PV = P @ V''.
// ---------------------------------------------------------------------------
__global__ __launch_bounds__(256) void out_kernel(
    const f16* __restrict__ Qh, const f16* __restrict__ Kh,
    const f16* __restrict__ Vt, float* __restrict__ out)
{
    __shared__ f16 Qs[128 * 64];   // 16KB; per-wave 4KB regions become P
    __shared__ f16 Ks[64 * 64];    // 8KB [k][d]
    __shared__ f16 Vs[64 * 64];    // 8KB [d][k-chunk]

    const int t = threadIdx.x, wv = t >> 6, lane = t & 63;
    const int lm = lane & 31, half = lane >> 5;
    const int bh = blockIdx.y, q0 = blockIdx.x * 128;
    const int b = bh >> 4, h = bh & 15;
    const size_t base  = (size_t)bh * SEQ * HDIM;
    const size_t vbase = (size_t)bh * HDIM * SEQ;

    const int srow = lane >> 3;
    const int sgr  = (lane & 7) ^ (srow & 7);

    // stage this wave's 32 Q rows
#pragma unroll
    for (int i = 0; i < 4; ++i) {
        int rr = wv * 32 + 8 * i;
        async16(Qs + rr * 64,
                Qh + base + (size_t)(q0 + rr + srow) * 64 + sgr * 8);
    }
    __syncthreads();

    f16x8 Qf[4];   // B-operand for S^T: B[n=q][k=d], pinned
#pragma unroll
    for (int kg = 0; kg < 4; ++kg)
        Qf[kg] = *(const f16x8*)&Qs[swz64(wv * 32 + lm, 2 * kg + half)];

    f32x16 oacc[2];
    oacc[0] = zero16(); oacc[1] = zero16();

    f16* Pw = Qs + wv * 32 * 64;   // per-wave P region [32 q][64 k], swizzled

    for (int it = 0; it < 32; ++it) {
        const int k0 = it * 64;
        __syncthreads();           // WAR on Ks/Vs
#pragma unroll
        for (int i = 0; i < 2; ++i) {
            int rr = wv * 16 + 8 * i;
            async16(Ks + rr * 64,
                    Kh + base + (size_t)(k0 + rr + srow) * 64 + sgr * 8);
            async16(Vs + rr * 64,
                    Vt + vbase + (size_t)(rr + srow) * SEQ + k0 + sgr * 8);
        }
        __syncthreads();

        // S^T tiles: D[m=k][n=q] = K . Q^T ; exp2 ; pack k-contiguous into Pw
#pragma unroll
        for (int kt = 0; kt < 2; ++kt) {
            f16x8 Kfr[4];
#pragma unroll
            for (int kg = 0; kg < 4; ++kg)
                Kfr[kg] = *(const f16x8*)&Ks[swz64(kt * 32 + lm, 2 * kg + half)];
            f32x16 st = zero16();
#pragma unroll
            for (int kg = 0; kg < 4; ++kg)
                st = mfma32(Kfr[kg], Qf[kg], st);
            const int row = lm;   // P row (q-local)
#pragma unroll
            for (int g = 0; g < 4; ++g) {
                union { f16x2 h2[2]; f16x4 h4; } u;
                u.h2[0] = pk2(exp2f(st[4*g+0]), exp2f(st[4*g+1]));
                u.h2[1] = pk2(exp2f(st[4*g+2]), exp2f(st[4*g+3]));
                *(f16x4*)&Pw[row * 64 + (((4*kt+g) ^ (row & 7)) << 3) + half * 4] = u.h4;
            }
        }

        // PV: D[m=q][n=d] = P @ V''  (same-wave DS ordering, no barrier)
#pragma unroll
        for (int kc = 0; kc < 4; ++kc) {
            f16x8 Pf  = *(const f16x8*)&Pw[lm * 64 + (((2*kc+half) ^ (lm & 7)) << 3)];
            f16x8 Vf0 = *(const f16x8*)&Vs[swz64(lm,      2 * kc + half)];
            f16x8 Vf1 = *(const f16x8*)&Vs[swz64(32 + lm, 2 * kc + half)];
            oacc[0] = mfma32(Pf, Vf0, oacc[0]);
            oacc[1] = mfma32(Pf, Vf1, oacc[1]);
        }
    }

    // store: C col = d (lane&31), rows = q pattern
#pragma unroll
    for (int dt = 0; dt < 2; ++dt) {
        int col = h * HDIM + dt * 32 + lm;
#pragma unroll
        for (int e = 0; e < 16; ++e) {
            int s = q0 + wv * 32 + (e & 3) + 8 * (e >> 2) + 4 * half;
            out[((size_t)b * SEQ + s) * EMBED + col] = oacc[dt][e] * 0.015625f;
        }
    }
}

extern "C" void kernel_launch(void* const* d_in, const int* in_sizes, int n_in,
                              void* d_out, int out_size, void* d_ws, size_t ws_size,
                              hipStream_t stream) {
    const float* x  = (const float*)d_in[0];
    const float* Wq = (const float*)d_in[1];
    const float* bq = (const float*)d_in[2];
    const float* Wk = (const float*)d_in[3];
    const float* bk = (const float*)d_in[4];
    const float* Wv = (const float*)d_in[5];
    const float* bv = (const float*)d_in[6];
    float* out = (float*)d_out;

    f16* xh = (f16*)d_ws;                          // 8.4M f16
    f16* Wh = xh + (size_t)ROWS * EMBED;           // 3.1M
    f16* Qh = Wh + (size_t)3 * EMBED * EMBED;      // 8.4M (pre-scaled by EXP2C)
    f16* Kh = Qh + (size_t)BH * SEQ * HDIM;        // 8.4M
    f16* Vt = Kh + (size_t)BH * SEQ * HDIM;        // 8.4M  [bh][d][s]

    cvt_kernel<<<(NX4 + 3 * NW4) / 256, 256, 0, stream>>>(x, Wq, Wk, Wv, xh, Wh);
    proj_kernel<<<dim3(ROWS / 128, 3 * EMBED / 128), 256, 0, stream>>>(
        xh, Wh, bq, bk, bv, Qh, Kh, Vt);
    stats_kernel<<<dim3(SEQ / 128, BH), 256, 0, stream>>>(Qh, Kh, Vt);
    out_kernel<<<dim3(SEQ / 128, BH), 256, 0, stream>>>(Qh, Kh, Vt, out);
}